// Round 4
// baseline (476.238 us; speedup 1.0000x reference)
//
#include <hip/hip_runtime.h>

// Spatially varying anisotropic 2D elastic wave sim, 384x384, 192 steps.
// Round 3: K=12 trapezoid fusion, restructured for LDS-pipe + phase-lock:
//  - (ux,uy) interleaved as float2 in LDS -> b64 exchange, 25 ops/thread/step
//  - stencil math on float2 (v_pk_fma_f32-friendly)
//  - 512 blocks x 192 threads (owned 12x24, staging 36x48) -> 2 blocks/CU,
//    so one block computes while the other drains LDS / waits at barrier
//  - state stored as float2 pairs (cur, old) in ws

#define NXg 384
#define NYg 384
#define NPT (NXg * NYg)
#define NFRAMES 48

#define OWNR 12
#define OWNC 24
#define HALO 12
#define TSR 36        // staging rows = OWNR + 2*HALO
#define TSC 48        // staging cols = OWNC + 2*HALO
#define KSTEPS 12
#define NLAUNCH 16

#define H_   1e-4
#define DT_  5e-9
#define RHO_ 1610.0

#define B11_LO 5e10f
#define B11_HI 2.5e11f
#define B22_LO 5e9f
#define B22_HI 5e10f
#define B12_LO 5e9f
#define B12_HI 5e10f
#define B16_LO 0.0f
#define B16_HI 6e10f
#define B26_LO 0.0f
#define B26_HI 2e10f
#define B66_LO 5e9f
#define B66_HI 3e10f

static __device__ __constant__ float kScale  = (float)(DT_ * DT_ / (H_ * H_) / RHO_);
static __device__ __constant__ float kSrcScl = (float)(DT_ * DT_ / RHO_);

__device__ __forceinline__ float clipf(float v, float lo, float hi) {
    return fminf(fmaxf(v, lo), hi);
}
__device__ __forceinline__ float2 f2(float x, float y) { return make_float2(x, y); }
__device__ __forceinline__ float2 fadd2(float2 a, float2 b) { return f2(a.x + b.x, a.y + b.y); }
__device__ __forceinline__ float2 fsub2(float2 a, float2 b) { return f2(a.x - b.x, a.y - b.y); }
__device__ __forceinline__ float2 fscl2(float s, float2 a) { return f2(s * a.x, s * a.y); }
__device__ __forceinline__ float2 ffma2(float s, float2 a, float2 b) {
    return f2(fmaf(s, a.x, b.x), fmaf(s, a.y, b.y));
}

// ws float layout:
// [0..7NPT): 7 coeff planes A11,A22,A12p66,A16,A26,A66,GS
// [7NPT..11NPT):  state set0  (cur float2[NPT], old float2[NPT])
// [11NPT..15NPT): state set1

__global__ __launch_bounds__(256)
void setup_kernel(const float* __restrict__ lc11, const float* __restrict__ lc12,
                  const float* __restrict__ lc16, const float* __restrict__ lc22,
                  const float* __restrict__ lc26, const float* __restrict__ lc66,
                  const float* __restrict__ gauss, float* __restrict__ ws) {
    int i = blockIdx.x * blockDim.x + threadIdx.x;
    if (i >= NPT) return;
    float C11 = clipf(expf(lc11[i]), B11_LO, B11_HI);
    float C12 = clipf(expf(lc12[i]), B12_LO, B12_HI);
    float C16 = clipf(expf(lc16[i]), B16_LO, B16_HI);
    float C22 = clipf(expf(lc22[i]), B22_LO, B22_HI);
    float C26 = clipf(expf(lc26[i]), B26_LO, B26_HI);
    float C66 = clipf(expf(lc66[i]), B66_LO, B66_HI);
    float s = kScale;
    ws[0 * NPT + i] = C11 * s;
    ws[1 * NPT + i] = C22 * s;
    ws[2 * NPT + i] = (C12 + C66) * s;
    ws[3 * NPT + i] = C16 * s;
    ws[4 * NPT + i] = C26 * s;
    ws[5 * NPT + i] = C66 * s;
    ws[6 * NPT + i] = gauss[i] * kSrcScl;
    float2* s0c = (float2*)(ws + 7 * (size_t)NPT);
    float2* s0o = s0c + NPT;
    s0c[i] = f2(0.0f, 0.0f);
    s0o[i] = f2(0.0f, 0.0f);
}

__global__ __launch_bounds__(192, 2)
void fused_kernel(const float* __restrict__ ws, const float* __restrict__ sig,
                  const float2* __restrict__ inCur, const float2* __restrict__ inOld,
                  float2* __restrict__ outCur, float2* __restrict__ outOld,
                  float* __restrict__ out, int L) {
    __shared__ float2 sb[2][TSR][TSC + 1];

    const int tid = threadIdx.x;
    const int tx = tid >> 4;          // 0..11 row group
    const int ty = tid & 15;          // 0..15 col group
    const int r0 = 3 * tx;
    const int c0 = 3 * ty;
    const int gx0 = blockIdx.y * OWNR - HALO;
    const int gy0 = blockIdx.x * OWNC - HALO;

    float2 cur[9], old[9];
    float a11[9], a22[9], a12p66[9], a16[9], a26[9], a66[9], gs[9];
    int gidx[9];

#pragma unroll
    for (int i = 0; i < 3; ++i) {
#pragma unroll
        for (int j = 0; j < 3; ++j) {
            int p = i * 3 + j;
            int gx = gx0 + r0 + i;
            int gy = gy0 + c0 + j;
            bool d = (unsigned)gx < (unsigned)NXg && (unsigned)gy < (unsigned)NYg;
            int g = d ? gx * NYg + gy : 0;
            gidx[p] = g;
            cur[p] = d ? inCur[g] : f2(0.0f, 0.0f);
            old[p] = d ? inOld[g] : f2(0.0f, 0.0f);
            // out-of-domain -> zero coeffs => point stays exactly 0
            a11[p]    = d ? ws[0 * NPT + g] : 0.0f;
            a22[p]    = d ? ws[1 * NPT + g] : 0.0f;
            a12p66[p] = d ? ws[2 * NPT + g] : 0.0f;
            a16[p]    = d ? ws[3 * NPT + g] : 0.0f;
            a26[p]    = d ? ws[4 * NPT + g] : 0.0f;
            a66[p]    = d ? ws[5 * NPT + g] : 0.0f;
            gs[p]     = d ? ws[6 * NPT + g] : 0.0f;
        }
    }

    // clamped halo coords (trapezoid garbage-tolerance at staging rim)
    const int rm = (r0 > 0) ? r0 - 1 : 0;
    const int rp = (r0 + 3 < TSR) ? r0 + 3 : TSR - 1;
    const int cm = (c0 > 0) ? c0 - 1 : 0;
    const int cp = (c0 + 3 < TSC) ? c0 + 3 : TSC - 1;

    const bool owned = (tx >= 4) && (tx < 8) && (ty >= 4) && (ty < 12);
    const int t0 = L * KSTEPS;

    // publish initial values into buffer 0
#pragma unroll
    for (int i = 0; i < 3; ++i)
#pragma unroll
        for (int j = 0; j < 3; ++j)
            sb[0][r0 + i][c0 + j] = cur[i * 3 + j];
    __syncthreads();

#pragma unroll 1
    for (int s = 1; s <= KSTEPS; ++s) {
        const float2 (*rb)[TSC + 1] = sb[(s - 1) & 1];
        float2 (*wb)[TSC + 1] = sb[s & 1];
        const float sig_t = sig[t0 + s - 1];

        // assemble 5x5 float2 window: own 3x3 from regs + 16 halo b64 reads
        float2 v[5][5];
#pragma unroll
        for (int i = 0; i < 3; ++i)
#pragma unroll
            for (int j = 0; j < 3; ++j)
                v[i + 1][j + 1] = cur[i * 3 + j];
        v[0][0] = rb[rm][cm];  v[0][4] = rb[rm][cp];
        v[4][0] = rb[rp][cm];  v[4][4] = rb[rp][cp];
#pragma unroll
        for (int j = 0; j < 3; ++j) {
            v[0][j + 1] = rb[rm][c0 + j];
            v[4][j + 1] = rb[rp][c0 + j];
            v[j + 1][0] = rb[r0 + j][cm];
            v[j + 1][4] = rb[r0 + j][cp];
        }

        // horizontal differences, shared between sxy of the 9 points
        float2 dh[5][3];
#pragma unroll
        for (int i = 0; i < 5; ++i)
#pragma unroll
            for (int j = 0; j < 3; ++j)
                dh[i][j] = fsub2(v[i][j + 2], v[i][j]);

#pragma unroll
        for (int i = 0; i < 3; ++i)
#pragma unroll
            for (int j = 0; j < 3; ++j) {
                int p = i * 3 + j;
                float2 c = v[i + 1][j + 1];
                float2 sxx = ffma2(-2.0f, c, fadd2(v[i][j + 1], v[i + 2][j + 1]));
                float2 syy = ffma2(-2.0f, c, fadd2(v[i + 1][j], v[i + 1][j + 2]));
                float2 sxy = fscl2(0.25f, fsub2(dh[i + 2][j], dh[i][j]));

                float lux = fmaf(a11[p], sxx.x,
                            fmaf(a66[p], syy.x,
                            fmaf(a12p66[p], sxy.y,
                            fmaf(a16[p], fmaf(2.0f, sxy.x, sxx.y),
                                 a26[p] * syy.y))));
                float luy = fmaf(a66[p], sxx.y,
                            fmaf(a22[p], syy.y,
                            fmaf(a12p66[p], sxy.x,
                            fmaf(a16[p], sxx.x,
                                 a26[p] * fmaf(2.0f, sxy.y, syy.x)))));

                float nx = fmaf(2.0f, c.x, lux) - old[p].x;
                float ny = fmaf(2.0f, c.y, fmaf(sig_t, gs[p], luy)) - old[p].y;
                old[p] = c;
                cur[p] = f2(nx, ny);
            }

        // frame output at global t = t0 + s - 1; t%4==3 <=> s%4==0
        if ((s & 3) == 0 && owned) {
            int f = 3 * L + (s >> 2) - 1;
            float* oux = out + (size_t)f * NPT;
            float* ouy = out + (size_t)(NFRAMES + f) * NPT;
#pragma unroll
            for (int p = 0; p < 9; ++p) {
                oux[gidx[p]] = cur[p].x;
                ouy[gidx[p]] = cur[p].y;
            }
        }

        // publish new values; ONE barrier per step (double buffered)
#pragma unroll
        for (int i = 0; i < 3; ++i)
#pragma unroll
            for (int j = 0; j < 3; ++j)
                wb[r0 + i][c0 + j] = cur[i * 3 + j];
        __syncthreads();
    }

    if (owned) {
#pragma unroll
        for (int p = 0; p < 9; ++p) {
            int g = gidx[p];
            outCur[g] = cur[p];
            outOld[g] = old[p];
        }
    }
}

extern "C" void kernel_launch(void* const* d_in, const int* in_sizes, int n_in,
                              void* d_out, int out_size, void* d_ws, size_t ws_size,
                              hipStream_t stream) {
    const float* lc11  = (const float*)d_in[0];
    const float* lc12  = (const float*)d_in[1];
    const float* lc16  = (const float*)d_in[2];
    const float* lc22  = (const float*)d_in[3];
    const float* lc26  = (const float*)d_in[4];
    const float* lc66  = (const float*)d_in[5];
    const float* gauss = (const float*)d_in[6];
    const float* sig   = (const float*)d_in[7];

    float* ws  = (float*)d_ws;
    float* out = (float*)d_out;

    setup_kernel<<<(NPT + 255) / 256, 256, 0, stream>>>(lc11, lc12, lc16, lc22,
                                                        lc26, lc66, gauss, ws);

    float2* set0c = (float2*)(ws + 7 * (size_t)NPT);
    float2* set0o = set0c + NPT;
    float2* set1c = (float2*)(ws + 11 * (size_t)NPT);
    float2* set1o = set1c + NPT;

    dim3 grid(NYg / OWNC, NXg / OWNR);  // (16, 32) = 512 blocks -> 2 per CU
    for (int L = 0; L < NLAUNCH; ++L) {
        float2* ic = (L & 1) ? set1c : set0c;
        float2* io = (L & 1) ? set1o : set0o;
        float2* oc = (L & 1) ? set0c : set1c;
        float2* oo = (L & 1) ? set0o : set1o;
        fused_kernel<<<grid, 192, 0, stream>>>(ws, sig, ic, io, oc, oo, out, L);
    }
}